// Round 4
// baseline (524.258 us; speedup 1.0000x reference)
//
#include <hip/hip_runtime.h>

typedef __attribute__((ext_vector_type(8))) short short8;
typedef __attribute__((ext_vector_type(4))) float floatx4;

#define CIN    192
#define COUTN  192
#define HWDIM  56
#define HWSZ   (56*56)
#define KWT    1728
#define TH     8
#define HY     10
#define PH     58
#define CK     32
#define NCHUNK 6
#define MT     64
#define HPC    (HY*PH*CK)   /* shorts per halo buffer: 18,560 */

// ws layout: xpack [b 32][cc 6][h' 58][x' 58][c 32] bf16 (chunk-swizzled within pixel);
//            wpack [og 3][cc 6][off 9][m 64][c 32] bf16
// Chunk swizzle: pixel P = h'*58 + x' holds 4x 16B chunks; logical channel-group g is
// stored at slot  g ^ ((P>>1)&3).  Consistent across conv tiles since gh0*58 % 8 == 0.
#define XPACK_SHORTS (32u*6u*58u*58u*32u)   /* 20,668,416 shorts = 41,336,832 B */
#define WPACK_SHORTS (3u*6u*9u*64u*32u)     /* 331,776 shorts = 663,552 B */
#define WS_NEEDED    ((size_t)(XPACK_SHORTS + WPACK_SHORTS) * 2u)

__device__ __forceinline__ short f2bf(float f) {
    union { float f; unsigned u; } v; v.f = f;
    unsigned u = v.u + 0x7FFFu + ((v.u >> 16) & 1u);  // RNE
    return (short)(u >> 16);
}

// pack two floats (lo=even channel, hi=odd channel) into one uint of 2x bf16, RNE
__device__ __forceinline__ unsigned pk2(float lo, float hi) {
    union { float f; unsigned u; } a, b;
    a.f = lo; b.f = hi;
    unsigned ua = a.u + 0x7FFFu + ((a.u >> 16) & 1u);
    unsigned ub = b.u + 0x7FFFu + ((b.u >> 16) & 1u);
    return (ua >> 16) | (ub & 0xFFFF0000u);
}

// ---------------- pre-pass: pack x (LDS transpose) + pack w, one merged kernel ----------------
#define XP_P 788   /* padded pitch (uints); 784 pixels + 4 pad -> <=2-way bank alias on reads */
#define PXBLOCKS (32*6*4)      /* 768 pack_x blocks */
#define PWTOT    (3*6*9*64*4)  /* 27,648 pack_w work items = 108 blocks */

__global__ __launch_bounds__(256)
void pack_xw(const float* __restrict__ x, const float* __restrict__ w,
             short* __restrict__ xp, short* __restrict__ wp) {
    __shared__ unsigned sp[16 * XP_P];                  // 50,432 B (pack_x path only)
    const int tid = threadIdx.x;

    if (blockIdx.x >= PXBLOCKS) {
        // ---- pack_w: [og][cc][off][m][c] bf16 ----
        int idx = (blockIdx.x - PXBLOCKS) * 256 + tid;
        if (idx < PWTOT) {
            int cg = idx & 3;
            int m  = (idx >> 2) & 63;
            int t  = idx >> 8;                          // og*54 + cc*9 + off
            int off = t % 9;  t /= 9;
            int cc  = t % 6;
            int og  = t / 6;
            short8 v;
#pragma unroll
            for (int k = 0; k < 8; ++k)
                v[k] = f2bf(w[(size_t)(og * 64 + m) * KWT + (cc * 32 + cg * 8 + k) * 9 + off]);
            *(short8*)(wp + (size_t)idx * 8) = v;
        }
        return;
    }

    const int bid = blockIdx.x;                         // b*24 + cc*4 + rg
    const int rg  = bid & 3;
    const int cc  = (bid >> 2) % 6;
    const int b   = bid / 24;
    const int h0  = rg * 14;                            // first input row of this group

    // ---- phase 1: global (coalesced) -> LDS, NCHW fp32 -> pair-interleaved bf16 ----
    const float* base = x + ((size_t)(b * CIN + cc * 32) * HWSZ + (size_t)h0 * HWDIM);
    for (int i = tid; i < 16 * 196; i += 256) {         // 16 channel pairs x 196 float4s
        int a = i / 196;                                // channel pair
        int j = i - a * 196;                            // float4 index within 784 pixels
        const float4 f0 = *(const float4*)(base + (size_t)(2 * a)     * HWSZ + j * 4);
        const float4 f1 = *(const float4*)(base + (size_t)(2 * a + 1) * HWSZ + j * 4);
        uint4 u;
        u.x = pk2(f0.x, f1.x);
        u.y = pk2(f0.y, f1.y);
        u.z = pk2(f0.z, f1.z);
        u.w = pk2(f0.w, f1.w);
        *(uint4*)&sp[a * XP_P + j * 4] = u;             // ds_write_b128, conflict-free
    }
    __syncthreads();

    // ---- phase 2: LDS -> global, [pair][pixel] -> [h'][x'][c] with zero x-borders ----
    // chunk slot within pixel is swizzled: s = g ^ ((P>>1)&3), P = padded pixel index
    short* orow = xp + (((size_t)(b * 6 + cc) * PH + (h0 + 1)) * PH) * CK;
    for (int i = tid; i < 14 * 58 * 4; i += 256) {      // 3248 short8 stores
        int g  = i & 3;                                 // logical channel group of 8
        int t  = i >> 2;
        int xq = t % 58;
        int r  = t / 58;                                // local row 0..13
        uint4 u = (uint4){0u, 0u, 0u, 0u};
        if (xq > 0 && xq < 57) {
            int wdx = r * 56 + xq - 1;
            u.x = sp[(4 * g + 0) * XP_P + wdx];
            u.y = sp[(4 * g + 1) * XP_P + wdx];
            u.z = sp[(4 * g + 2) * XP_P + wdx];
            u.w = sp[(4 * g + 3) * XP_P + wdx];
        }
        int P = (h0 + 1 + r) * PH + xq;                 // padded-global pixel index
        int s = g ^ ((P >> 1) & 3);                     // swizzled chunk slot
        *(uint4*)(orow + ((size_t)r * PH + xq) * CK + s * 8) = u;
    }

    // ---- zero pad rows h'=0 (rg==0) and h'=57 (rg==3) ---- (all-zero: swizzle irrelevant)
    if (rg == 0 || rg == 3) {
        int hq = (rg == 0) ? 0 : 57;
        short* prow = xp + (((size_t)(b * 6 + cc) * PH + hq) * PH) * CK;
        for (int i = tid; i < 58 * 4; i += 256)
            *(uint4*)(prow + (size_t)i * 8) = (uint4){0u, 0u, 0u, 0u};
    }
}

// ---------------- main: implicit-GEMM conv, double-buffered halo (T3 2-phase) ----------------
// TH=8 rows/block, 8 waves (512 thr), LDS = 2 x 37,120 B -> 2 blocks/CU, 16 waves/CU.
// Per chunk: issue stage(next buf) BEFORE compute(cur buf); ONE __syncthreads per chunk.
// The vmcnt(0) drain at the barrier is ~free: stage loads were issued a full compute
// phase (~1500+ cyc) earlier (round-3 post-mortem: single-buffered structure exposed
// staging 6x/block and sat at 2x the LDS-BW floor).
// Grid 672 = 8 xcd x 28 tiles x 3 og: og-partner blocks adjacent on the SAME XCD.
__global__ __launch_bounds__(512, 4)
void conv_main(const short* __restrict__ xp, const short* __restrict__ wp,
               const float* __restrict__ bias, float* __restrict__ out) {
    __shared__ __align__(16) short sh[2 * HPC];         // 74,240 B

    const int tid  = threadIdx.x;
    const int u    = blockIdx.x;                        // 0..671
    const int xcd  = u & 7;
    const int slot = u >> 3;                            // 0..83
    const int og   = slot % 3;
    const int tile = xcd * 28 + slot / 3;               // 0..223
    const int bx   = tile % 7;
    const int bb   = tile / 7;
    const int gh0  = bx * TH;
    const int lane = tid & 63;
    const int wave = tid >> 6;                          // 0..7
    const int wm   = wave >> 2;                         // 0..1 : cout half
    const int wn   = wave & 3;                          // 0..3 : pixel quarter
    const int g    = lane >> 4;
    const int col  = lane & 15;

    int pnt[7];
#pragma unroll
    for (int nt = 0; nt < 7; ++nt) {
        int l = wn * 112 + nt * 16 + col;               // 0..447
        pnt[nt] = (l / 56) * PH + (l % 56);             // tile-local pixel index
    }

    floatx4 acc[2][7];
#pragma unroll
    for (int mt = 0; mt < 2; ++mt)
#pragma unroll
        for (int nt = 0; nt < 7; ++nt)
            acc[mt][nt] = (floatx4){0.f, 0.f, 0.f, 0.f};

    const short8* wpk = (const short8*)wp;
    const int wlbase = wave * 64;                       // wave-uniform lds chunk base
    const short* srcb = xp + ((size_t)bb * 6 * (PH * PH) + (size_t)gh0 * PH) * CK;

#define STAGE(dstbuf, ccc)                                                              \
    do {                                                                                \
        const short* _src = srcb + (size_t)(ccc) * (PH * PH) * CK;                      \
        short* _dst = sh + (dstbuf) * HPC;                                              \
        _Pragma("unroll")                                                               \
        for (int _j = 0; _j < 5; ++_j) {                                                \
            int _idx = _j * 512 + tid;                                                  \
            if (_idx < HY * PH * 4) {                                                   \
                __builtin_amdgcn_global_load_lds(                                       \
                    (const __attribute__((address_space(1))) void*)(_src + (size_t)_idx * 8), \
                    (__attribute__((address_space(3))) void*)(_dst + (_j * 512 + wlbase) * 8), \
                    16, 0, 0);                                                          \
            }                                                                           \
        }                                                                               \
    } while (0)

    // prologue: stage chunk 0 into buf 0, load afr for chunk 0
    short8 afr[9][2];
    STAGE(0, 0);
#pragma unroll
    for (int off = 0; off < 9; ++off)
#pragma unroll
        for (int mt = 0; mt < 2; ++mt)
            afr[off][mt] = wpk[((og * 6 + 0) * 9 + off) * 256 + (wm * 32 + mt * 16 + col) * 4 + g];
    __syncthreads();                                    // vmcnt(0): stage0 + afr0 done

    for (int cc = 0; cc < NCHUNK; ++cc) {
        const short* cur = sh + (cc & 1) * HPC;

        if (cc + 1 < NCHUNK) STAGE((cc + 1) & 1, cc + 1);   // async into other buffer

#pragma unroll
        for (int off = 0; off < 9; ++off) {
            const int doff = (off / 3) * PH + (off % 3);
#pragma unroll
            for (int nt = 0; nt < 7; ++nt) {
                int p = pnt[nt] + doff;                 // tile-local pixel (== global mod 8)
                int s = ((p >> 1) & 3) ^ g;             // de-swizzled chunk slot
                short8 bfr = *(const short8*)&cur[(p << 5) + (s << 3)];
                acc[0][nt] = __builtin_amdgcn_mfma_f32_16x16x32_bf16(afr[off][0], bfr, acc[0][nt], 0, 0, 0);
                acc[1][nt] = __builtin_amdgcn_mfma_f32_16x16x32_bf16(afr[off][1], bfr, acc[1][nt], 0, 0, 0);
            }
        }

        if (cc + 1 < NCHUNK) {
            // next chunk's weights (L2-hit); latency lands under the barrier wait
#pragma unroll
            for (int off = 0; off < 9; ++off)
#pragma unroll
                for (int mt = 0; mt < 2; ++mt)
                    afr[off][mt] = wpk[((og * 6 + cc + 1) * 9 + off) * 256 + (wm * 32 + mt * 16 + col) * 4 + g];
            __syncthreads();                            // drains next stage; cur buf free
        }
    }
#undef STAGE

    // epilogue: D row = g*4 + r, col = lane&15
#pragma unroll
    for (int mt = 0; mt < 2; ++mt) {
        int o = og * 64 + wm * 32 + mt * 16 + g * 4;
#pragma unroll
        for (int nt = 0; nt < 7; ++nt) {
            int l  = wn * 112 + nt * 16 + col;
            int h  = gh0 + l / 56;
            int ww = l % 56;
            size_t base = ((size_t)(bb * COUTN + o) * HWDIM + h) * HWDIM + ww;
            floatx4 v = acc[mt][nt];
#pragma unroll
            for (int r2 = 0; r2 < 4; ++r2)
                out[base + (size_t)r2 * HWSZ] = v[r2] + bias[o + r2];
        }
    }
}

// ---------------- fallback (round-1 kernel) if ws too small ----------------
__global__ __launch_bounds__(256, 2)
void conv3x3_fb(const float* __restrict__ x, const float* __restrict__ w,
                const float* __restrict__ bias, float* __restrict__ out) {
    __shared__ __align__(16) short sh_halo[6 * PH * CK];
    __shared__ __align__(16) short sh_w[9 * MT * CK];
    const int tid = threadIdx.x;
    const int gh0 = blockIdx.x * 4;
    const int o0  = blockIdx.y * MT;
    const int bb  = blockIdx.z;
    const int lane = tid & 63, wave = tid >> 6;
    const int wm = wave >> 1, wn = wave & 1;
    const int g = lane >> 4, col = lane & 15;
    int ly[7], lx[7];
#pragma unroll
    for (int nt = 0; nt < 7; ++nt) {
        int l = wn * 112 + nt * 16 + col;
        ly[nt] = l / 56; lx[nt] = l % 56;
    }
    floatx4 acc[2][7];
#pragma unroll
    for (int mt = 0; mt < 2; ++mt)
#pragma unroll
        for (int nt = 0; nt < 7; ++nt) acc[mt][nt] = (floatx4){0.f,0.f,0.f,0.f};
    for (int cc = 0; cc < NCHUNK; ++cc) {
        const int c0 = cc * CK;
        if (cc) __syncthreads();
        for (int i = tid; i < 4 * 6 * PH; i += 256) {
            int xx = i % PH, r = i / PH, y = r % 6, cg = r / 6;
            int gh = gh0 + y - 1, gw = xx - 1;
            bool ok = ((unsigned)gh < 56u) & ((unsigned)gw < 56u);
            const float* src = x + ((size_t)(bb * CIN + c0 + cg * 8) * HWDIM + gh) * HWDIM + gw;
            short8 v;
#pragma unroll
            for (int k = 0; k < 8; ++k) v[k] = f2bf(ok ? src[k * HWSZ] : 0.f);
            *(short8*)&sh_halo[(y * PH + xx) * CK + ((cg ^ ((xx >> 1) & 3)) << 3)] = v;
        }
        for (int i = tid; i < 9 * MT * 4; i += 256) {
            int cg = i & 3, off = (i >> 2) % 9, m = i / 36;
            const float* src = w + (size_t)(o0 + m) * KWT + (c0 + cg * 8) * 9 + off;
            short8 v;
#pragma unroll
            for (int k = 0; k < 8; ++k) v[k] = f2bf(src[k * 9]);
            *(short8*)&sh_w[(off * MT + m) * CK + ((cg ^ ((m >> 1) & 3)) << 3)] = v;
        }
        __syncthreads();
#pragma unroll
        for (int off = 0; off < 9; ++off) {
            const int di = off / 3, dj = off % 3;
            short8 a[2];
#pragma unroll
            for (int mt = 0; mt < 2; ++mt) {
                int m = wm * 32 + mt * 16 + col;
                a[mt] = *(const short8*)&sh_w[(off * MT + m) * CK + ((g ^ ((m >> 1) & 3)) << 3)];
            }
#pragma unroll
            for (int nt = 0; nt < 7; ++nt) {
                int yy = ly[nt] + di, xpp = lx[nt] + dj;
                short8 bfr = *(const short8*)&sh_halo[(yy * PH + xpp) * CK + ((g ^ ((xpp >> 1) & 3)) << 3)];
                acc[0][nt] = __builtin_amdgcn_mfma_f32_16x16x32_bf16(a[0], bfr, acc[0][nt], 0, 0, 0);
                acc[1][nt] = __builtin_amdgcn_mfma_f32_16x16x32_bf16(a[1], bfr, acc[1][nt], 0, 0, 0);
            }
        }
    }
#pragma unroll
    for (int mt = 0; mt < 2; ++mt) {
        int o = o0 + wm * 32 + mt * 16 + g * 4;
#pragma unroll
        for (int nt = 0; nt < 7; ++nt) {
            int l = wn * 112 + nt * 16 + col;
            int h = gh0 + l / 56, ww = l % 56;
            size_t base = ((size_t)(bb * COUTN + o) * HWDIM + h) * HWDIM + ww;
            floatx4 v = acc[mt][nt];
#pragma unroll
            for (int r2 = 0; r2 < 4; ++r2)
                out[base + (size_t)r2 * HWSZ] = v[r2] + bias[o + r2];
        }
    }
}

extern "C" void kernel_launch(void* const* d_in, const int* in_sizes, int n_in,
                              void* d_out, int out_size, void* d_ws, size_t ws_size,
                              hipStream_t stream) {
    const float* x  = (const float*)d_in[0];
    const float* wt = (const float*)d_in[1];
    const float* bi = (const float*)d_in[2];
    float* out = (float*)d_out;

    if (ws_size >= WS_NEEDED) {
        short* xpk = (short*)d_ws;
        short* wpk = xpk + XPACK_SHORTS;
        pack_xw<<<PXBLOCKS + (PWTOT + 255) / 256, 256, 0, stream>>>(x, wt, xpk, wpk);
        conv_main<<<dim3(672), dim3(512), 0, stream>>>(xpk, wpk, bi, out);
    } else {
        conv3x3_fb<<<dim3(14, 3, 32), dim3(256), 0, stream>>>(x, wt, bi, out);
    }
}

// Round 5
// 252.175 us; speedup vs baseline: 2.0789x; 2.0789x over previous
//
#include <hip/hip_runtime.h>

typedef __attribute__((ext_vector_type(8))) short short8;
typedef __attribute__((ext_vector_type(4))) float floatx4;

#define CIN    192
#define COUTN  192
#define HWDIM  56
#define HWSZ   (56*56)
#define KWT    1728
#define TH     4
#define HY     6
#define PH     58
#define CK     32
#define NCHUNK 6
#define MT     64
#define HPC    (HY*PH*CK)   /* shorts per halo buffer: 11,136 (22,272 B) */

// ws layout: xpack [b 32][cc 6][h' 58][x' 58][c 32] bf16 (chunk-swizzled within pixel);
//            wpack [og 3][cc 6][off 9][m 64][c 32] bf16
// Chunk swizzle: pixel P = h'*58 + x' holds 4x 16B chunks; logical channel-group g is
// stored at slot  g ^ ((P>>1)&3).  Consistent across conv tiles since gh0*58 % 8 == 0.
#define XPACK_SHORTS (32u*6u*58u*58u*32u)   /* 20,668,416 shorts = 41,336,832 B */
#define WPACK_SHORTS (3u*6u*9u*64u*32u)     /* 331,776 shorts = 663,552 B */
#define WS_NEEDED    ((size_t)(XPACK_SHORTS + WPACK_SHORTS) * 2u)

__device__ __forceinline__ short f2bf(float f) {
    union { float f; unsigned u; } v; v.f = f;
    unsigned u = v.u + 0x7FFFu + ((v.u >> 16) & 1u);  // RNE
    return (short)(u >> 16);
}

// pack two floats (lo=even channel, hi=odd channel) into one uint of 2x bf16, RNE
__device__ __forceinline__ unsigned pk2(float lo, float hi) {
    union { float f; unsigned u; } a, b;
    a.f = lo; b.f = hi;
    unsigned ua = a.u + 0x7FFFu + ((a.u >> 16) & 1u);
    unsigned ub = b.u + 0x7FFFu + ((b.u >> 16) & 1u);
    return (ua >> 16) | (ub & 0xFFFF0000u);
}

// ---------------- pre-pass: pack x (LDS transpose) + pack w, one merged kernel ----------------
#define XP_P 788   /* padded pitch (uints); 784 pixels + 4 pad -> <=2-way bank alias on reads */
#define PXBLOCKS (32*6*4)      /* 768 pack_x blocks */
#define PWTOT    (3*6*9*64*4)  /* 27,648 pack_w work items = 108 blocks */

__global__ __launch_bounds__(256)
void pack_xw(const float* __restrict__ x, const float* __restrict__ w,
             short* __restrict__ xp, short* __restrict__ wp) {
    __shared__ unsigned sp[16 * XP_P];                  // 50,432 B (pack_x path only)
    const int tid = threadIdx.x;

    if (blockIdx.x >= PXBLOCKS) {
        // ---- pack_w: [og][cc][off][m][c] bf16 ----
        int idx = (blockIdx.x - PXBLOCKS) * 256 + tid;
        if (idx < PWTOT) {
            int cg = idx & 3;
            int m  = (idx >> 2) & 63;
            int t  = idx >> 8;                          // og*54 + cc*9 + off
            int off = t % 9;  t /= 9;
            int cc  = t % 6;
            int og  = t / 6;
            short8 v;
#pragma unroll
            for (int k = 0; k < 8; ++k)
                v[k] = f2bf(w[(size_t)(og * 64 + m) * KWT + (cc * 32 + cg * 8 + k) * 9 + off]);
            *(short8*)(wp + (size_t)idx * 8) = v;
        }
        return;
    }

    const int bid = blockIdx.x;                         // b*24 + cc*4 + rg
    const int rg  = bid & 3;
    const int cc  = (bid >> 2) % 6;
    const int b   = bid / 24;
    const int h0  = rg * 14;                            // first input row of this group

    // ---- phase 1: global (coalesced) -> LDS, NCHW fp32 -> pair-interleaved bf16 ----
    const float* base = x + ((size_t)(b * CIN + cc * 32) * HWSZ + (size_t)h0 * HWDIM);
    for (int i = tid; i < 16 * 196; i += 256) {         // 16 channel pairs x 196 float4s
        int a = i / 196;                                // channel pair
        int j = i - a * 196;                            // float4 index within 784 pixels
        const float4 f0 = *(const float4*)(base + (size_t)(2 * a)     * HWSZ + j * 4);
        const float4 f1 = *(const float4*)(base + (size_t)(2 * a + 1) * HWSZ + j * 4);
        uint4 u;
        u.x = pk2(f0.x, f1.x);
        u.y = pk2(f0.y, f1.y);
        u.z = pk2(f0.z, f1.z);
        u.w = pk2(f0.w, f1.w);
        *(uint4*)&sp[a * XP_P + j * 4] = u;             // ds_write_b128, conflict-free
    }
    __syncthreads();

    // ---- phase 2: LDS -> global, [pair][pixel] -> [h'][x'][c] with zero x-borders ----
    // chunk slot within pixel is swizzled: s = g ^ ((P>>1)&3), P = padded pixel index
    short* orow = xp + (((size_t)(b * 6 + cc) * PH + (h0 + 1)) * PH) * CK;
    for (int i = tid; i < 14 * 58 * 4; i += 256) {      // 3248 short8 stores
        int g  = i & 3;                                 // logical channel group of 8
        int t  = i >> 2;
        int xq = t % 58;
        int r  = t / 58;                                // local row 0..13
        uint4 u = (uint4){0u, 0u, 0u, 0u};
        if (xq > 0 && xq < 57) {
            int wdx = r * 56 + xq - 1;
            u.x = sp[(4 * g + 0) * XP_P + wdx];
            u.y = sp[(4 * g + 1) * XP_P + wdx];
            u.z = sp[(4 * g + 2) * XP_P + wdx];
            u.w = sp[(4 * g + 3) * XP_P + wdx];
        }
        int P = (h0 + 1 + r) * PH + xq;                 // padded-global pixel index
        int s = g ^ ((P >> 1) & 3);                     // swizzled chunk slot
        *(uint4*)(orow + ((size_t)r * PH + xq) * CK + s * 8) = u;
    }

    // ---- zero pad rows h'=0 (rg==0) and h'=57 (rg==3) ---- (all-zero: swizzle irrelevant)
    if (rg == 0 || rg == 3) {
        int hq = (rg == 0) ? 0 : 57;
        short* prow = xp + (((size_t)(b * 6 + cc) * PH + hq) * PH) * CK;
        for (int i = tid; i < 58 * 4; i += 256)
            *(uint4*)(prow + (size_t)i * 8) = (uint4){0u, 0u, 0u, 0u};
    }
}

// ---------------- main: implicit-GEMM conv, double-buffered halo (T3 minimal 2-phase) ----------------
// ROUND-3 GEOMETRY UNTOUCHED (256 thr, TH=4, launch_bounds(256,2) -> VGPR 112, no spill;
// round-4 lesson: 512 thr + launch_bounds(512,4) forced VGPR=64 and spilled acc/afr to
// scratch, 1.1 GB HBM scratch traffic).  Only the schedule changes:
//   per chunk: STAGE(next chunk -> other buffer)  ->  compute(cur)  ->  afr(next)  ->  ONE barrier.
// The barrier's vmcnt(0) drain now lands a full compute phase (~2400 cyc) after the stage
// issue, instead of immediately after it (round-3: 2 barriers/chunk, stage exposed 6x).
// LDS 2x22,272 B = 44.5 KB -> 3 blocks/CU (12 waves/CU); intra-block stage||compute overlap
// replaces the cross-block overlap that the 4-blocks/CU single-buffer relied on.
// Grid 1344 = 8 xcd x 56 slots: og-partner blocks adjacent on the SAME XCD (L2-hit xp).
__global__ __launch_bounds__(256, 2)
void conv_main(const short* __restrict__ xp, const short* __restrict__ wp,
               const float* __restrict__ bias, float* __restrict__ out) {
    __shared__ __align__(16) short sh[2 * HPC];         // 44,544 B

    const int tid  = threadIdx.x;
    const int u    = blockIdx.x;                        // 0..1343
    const int xcd  = u & 7;
    const int slot = u >> 3;                            // 0..167
    const int og   = slot % 3;
    const int tile = xcd * 56 + slot / 3;               // 0..447
    const int bx   = tile % 14;
    const int bb   = tile / 14;
    const int gh0  = bx * TH;
    const int lane = tid & 63;
    const int wave = tid >> 6;
    const int wm   = wave >> 1;
    const int wn   = wave & 1;
    const int g    = lane >> 4;
    const int col  = lane & 15;

    int pnt[7];
#pragma unroll
    for (int nt = 0; nt < 7; ++nt) {
        int l = wn * 112 + nt * 16 + col;
        pnt[nt] = (l / 56) * PH + (l % 56);             // tile-local pixel index
    }

    floatx4 acc[2][7];
#pragma unroll
    for (int mt = 0; mt < 2; ++mt)
#pragma unroll
        for (int nt = 0; nt < 7; ++nt)
            acc[mt][nt] = (floatx4){0.f, 0.f, 0.f, 0.f};

    const short8* wpk = (const short8*)wp;
    const int wlbase = wave * 64;                       // wave-uniform lds chunk base
    const short* srcb = xp + ((size_t)bb * 6 * (PH * PH) + (size_t)gh0 * PH) * CK;

#define STAGE(dstbuf, ccc)                                                              \
    do {                                                                                \
        const short* _src = srcb + (size_t)(ccc) * (PH * PH) * CK;                      \
        short* _dst = sh + (dstbuf) * HPC;                                              \
        _Pragma("unroll")                                                               \
        for (int _j = 0; _j < 6; ++_j) {                                                \
            int _idx = _j * 256 + tid;                                                  \
            if (_idx < HY * PH * 4) {                    /* 1392 16B chunks */          \
                __builtin_amdgcn_global_load_lds(                                       \
                    (const __attribute__((address_space(1))) void*)(_src + (size_t)_idx * 8), \
                    (__attribute__((address_space(3))) void*)(_dst + (_j * 256 + wlbase) * 8), \
                    16, 0, 0);                                                          \
            }                                                                           \
        }                                                                               \
    } while (0)

    // prologue: stage chunk 0 into buf 0, load chunk-0 weights
    short8 afr[9][2];
    STAGE(0, 0);
#pragma unroll
    for (int off = 0; off < 9; ++off)
#pragma unroll
        for (int mt = 0; mt < 2; ++mt)
            afr[off][mt] = wpk[((og * 6 + 0) * 9 + off) * 256 + (wm * 32 + mt * 16 + col) * 4 + g];
    __syncthreads();                                    // vmcnt(0): stage0 + afr0 done

    for (int cc = 0; cc < NCHUNK; ++cc) {
        const short* cur = sh + (cc & 1) * HPC;

        if (cc + 1 < NCHUNK) STAGE((cc + 1) & 1, cc + 1);   // async into other buffer

#pragma unroll
        for (int off = 0; off < 9; ++off) {
            const int doff = (off / 3) * PH + (off % 3);
#pragma unroll
            for (int nt = 0; nt < 7; ++nt) {
                int p = pnt[nt] + doff;                 // tile-local pixel (== global mod 8)
                int s = ((p >> 1) & 3) ^ g;             // de-swizzled chunk slot
                short8 bfr = *(const short8*)&cur[(p << 5) + (s << 3)];
                acc[0][nt] = __builtin_amdgcn_mfma_f32_16x16x32_bf16(afr[off][0], bfr, acc[0][nt], 0, 0, 0);
                acc[1][nt] = __builtin_amdgcn_mfma_f32_16x16x32_bf16(afr[off][1], bfr, acc[1][nt], 0, 0, 0);
            }
        }

        if (cc + 1 < NCHUNK) {
            // next chunk's weights (L2-hit); latency lands under the barrier wait
#pragma unroll
            for (int off = 0; off < 9; ++off)
#pragma unroll
                for (int mt = 0; mt < 2; ++mt)
                    afr[off][mt] = wpk[((og * 6 + cc + 1) * 9 + off) * 256 + (wm * 32 + mt * 16 + col) * 4 + g];
            __syncthreads();                            // ONE barrier/chunk: drains stage(next)+afr(next)
        }
    }
#undef STAGE

    // epilogue: D row = g*4 + r, col = lane&15
#pragma unroll
    for (int mt = 0; mt < 2; ++mt) {
        int o = og * 64 + wm * 32 + mt * 16 + g * 4;
#pragma unroll
        for (int nt = 0; nt < 7; ++nt) {
            int l  = wn * 112 + nt * 16 + col;
            int h  = gh0 + l / 56;
            int ww = l % 56;
            size_t base = ((size_t)(bb * COUTN + o) * HWDIM + h) * HWDIM + ww;
            floatx4 v = acc[mt][nt];
#pragma unroll
            for (int r2 = 0; r2 < 4; ++r2)
                out[base + (size_t)r2 * HWSZ] = v[r2] + bias[o + r2];
        }
    }
}

// ---------------- fallback (round-1 kernel) if ws too small ----------------
__global__ __launch_bounds__(256, 2)
void conv3x3_fb(const float* __restrict__ x, const float* __restrict__ w,
                const float* __restrict__ bias, float* __restrict__ out) {
    __shared__ __align__(16) short sh_halo[HY * PH * CK];
    __shared__ __align__(16) short sh_w[9 * MT * CK];
    const int tid = threadIdx.x;
    const int gh0 = blockIdx.x * TH;
    const int o0  = blockIdx.y * MT;
    const int bb  = blockIdx.z;
    const int lane = tid & 63, wave = tid >> 6;
    const int wm = wave >> 1, wn = wave & 1;
    const int g = lane >> 4, col = lane & 15;
    int ly[7], lx[7];
#pragma unroll
    for (int nt = 0; nt < 7; ++nt) {
        int l = wn * 112 + nt * 16 + col;
        ly[nt] = l / 56; lx[nt] = l % 56;
    }
    floatx4 acc[2][7];
#pragma unroll
    for (int mt = 0; mt < 2; ++mt)
#pragma unroll
        for (int nt = 0; nt < 7; ++nt) acc[mt][nt] = (floatx4){0.f,0.f,0.f,0.f};
    for (int cc = 0; cc < NCHUNK; ++cc) {
        const int c0 = cc * CK;
        if (cc) __syncthreads();
        for (int i = tid; i < 4 * HY * PH; i += 256) {
            int xx = i % PH, r = i / PH, y = r % HY, cg = r / HY;
            int gh = gh0 + y - 1, gw = xx - 1;
            bool ok = ((unsigned)gh < 56u) & ((unsigned)gw < 56u);
            const float* src = x + ((size_t)(bb * CIN + c0 + cg * 8) * HWDIM + gh) * HWDIM + gw;
            short8 v;
#pragma unroll
            for (int k = 0; k < 8; ++k) v[k] = f2bf(ok ? src[k * HWSZ] : 0.f);
            *(short8*)&sh_halo[(y * PH + xx) * CK + ((cg ^ ((xx >> 1) & 3)) << 3)] = v;
        }
        for (int i = tid; i < 9 * MT * 4; i += 256) {
            int cg = i & 3, off = (i >> 2) % 9, m = i / 36;
            const float* src = w + (size_t)(o0 + m) * KWT + (c0 + cg * 8) * 9 + off;
            short8 v;
#pragma unroll
            for (int k = 0; k < 8; ++k) v[k] = f2bf(src[k * 9]);
            *(short8*)&sh_w[(off * MT + m) * CK + ((cg ^ ((m >> 1) & 3)) << 3)] = v;
        }
        __syncthreads();
#pragma unroll
        for (int off = 0; off < 9; ++off) {
            const int di = off / 3, dj = off % 3;
            short8 a[2];
#pragma unroll
            for (int mt = 0; mt < 2; ++mt) {
                int m = wm * 32 + mt * 16 + col;
                a[mt] = *(const short8*)&sh_w[(off * MT + m) * CK + ((g ^ ((m >> 1) & 3)) << 3)];
            }
#pragma unroll
            for (int nt = 0; nt < 7; ++nt) {
                int yy = ly[nt] + di, xpp = lx[nt] + dj;
                short8 bfr = *(const short8*)&sh_halo[(yy * PH + xpp) * CK + ((g ^ ((xpp >> 1) & 3)) << 3)];
                acc[0][nt] = __builtin_amdgcn_mfma_f32_16x16x32_bf16(a[0], bfr, acc[0][nt], 0, 0, 0);
                acc[1][nt] = __builtin_amdgcn_mfma_f32_16x16x32_bf16(a[1], bfr, acc[1][nt], 0, 0, 0);
            }
        }
    }
#pragma unroll
    for (int mt = 0; mt < 2; ++mt) {
        int o = o0 + wm * 32 + mt * 16 + g * 4;
#pragma unroll
        for (int nt = 0; nt < 7; ++nt) {
            int l = wn * 112 + nt * 16 + col;
            int h = gh0 + l / 56, ww = l % 56;
            size_t base = ((size_t)(bb * COUTN + o) * HWDIM + h) * HWDIM + ww;
            floatx4 v = acc[mt][nt];
#pragma unroll
            for (int r2 = 0; r2 < 4; ++r2)
                out[base + (size_t)r2 * HWSZ] = v[r2] + bias[o + r2];
        }
    }
}

extern "C" void kernel_launch(void* const* d_in, const int* in_sizes, int n_in,
                              void* d_out, int out_size, void* d_ws, size_t ws_size,
                              hipStream_t stream) {
    const float* x  = (const float*)d_in[0];
    const float* wt = (const float*)d_in[1];
    const float* bi = (const float*)d_in[2];
    float* out = (float*)d_out;

    if (ws_size >= WS_NEEDED) {
        short* xpk = (short*)d_ws;
        short* wpk = xpk + XPACK_SHORTS;
        pack_xw<<<PXBLOCKS + (PWTOT + 255) / 256, 256, 0, stream>>>(x, wt, xpk, wpk);
        conv_main<<<dim3(1344), dim3(256), 0, stream>>>(xpk, wpk, bi, out);
    } else {
        conv3x3_fb<<<dim3(14, 3, 32), dim3(256), 0, stream>>>(x, wt, bi, out);
    }
}

// Round 6
// 236.647 us; speedup vs baseline: 2.2154x; 1.0656x over previous
//
#include <hip/hip_runtime.h>

typedef __attribute__((ext_vector_type(8))) short short8;
typedef __attribute__((ext_vector_type(4))) float floatx4;

#define CIN    192
#define COUTN  192
#define HWDIM  56
#define HWSZ   (56*56)
#define KWT    1728
#define TH     4
#define HY     6
#define PH     58
#define CK     32
#define NCHUNK 6
#define MT     64
#define HPC    (HY*PH*CK)   /* shorts per halo buffer: 11,136 (22,272 B) */

// ws layout: xpack [b 32][cc 6][h' 58][x' 58][c 32] bf16 (chunk-swizzled within pixel);
//            wpack [og 3][cc 6][off 9][m 64][c 32] bf16
// Chunk swizzle: pixel P = h'*58 + x' holds 4x 16B chunks; logical channel-group g is
// stored at slot  g ^ ((P>>1)&3).  Consistent across conv tiles since gh0*58 % 8 == 0.
#define XPACK_SHORTS (32u*6u*58u*58u*32u)   /* 20,668,416 shorts = 41,336,832 B */
#define WPACK_SHORTS (3u*6u*9u*64u*32u)     /* 331,776 shorts = 663,552 B */
#define WS_NEEDED    ((size_t)(XPACK_SHORTS + WPACK_SHORTS) * 2u)

__device__ __forceinline__ short f2bf(float f) {
    union { float f; unsigned u; } v; v.f = f;
    unsigned u = v.u + 0x7FFFu + ((v.u >> 16) & 1u);  // RNE
    return (short)(u >> 16);
}

// pack two floats (lo=even channel, hi=odd channel) into one uint of 2x bf16, RNE
__device__ __forceinline__ unsigned pk2(float lo, float hi) {
    union { float f; unsigned u; } a, b;
    a.f = lo; b.f = hi;
    unsigned ua = a.u + 0x7FFFu + ((a.u >> 16) & 1u);
    unsigned ub = b.u + 0x7FFFu + ((b.u >> 16) & 1u);
    return (ua >> 16) | (ub & 0xFFFF0000u);
}

// ---------------- pre-pass: pack x (LDS transpose) + pack w, one merged kernel ----------------
#define XP_P 788   /* padded pitch (uints); 784 pixels + 4 pad -> <=2-way bank alias on reads */
#define PXBLOCKS (32*6*4)      /* 768 pack_x blocks */
#define PWTOT    (3*6*9*64*4)  /* 27,648 pack_w work items = 108 blocks */

__global__ __launch_bounds__(256)
void pack_xw(const float* __restrict__ x, const float* __restrict__ w,
             short* __restrict__ xp, short* __restrict__ wp) {
    __shared__ unsigned sp[16 * XP_P];                  // 50,432 B (pack_x path only)
    const int tid = threadIdx.x;

    if (blockIdx.x >= PXBLOCKS) {
        // ---- pack_w: [og][cc][off][m][c] bf16 ----
        int idx = (blockIdx.x - PXBLOCKS) * 256 + tid;
        if (idx < PWTOT) {
            int cg = idx & 3;
            int m  = (idx >> 2) & 63;
            int t  = idx >> 8;                          // og*54 + cc*9 + off
            int off = t % 9;  t /= 9;
            int cc  = t % 6;
            int og  = t / 6;
            short8 v;
#pragma unroll
            for (int k = 0; k < 8; ++k)
                v[k] = f2bf(w[(size_t)(og * 64 + m) * KWT + (cc * 32 + cg * 8 + k) * 9 + off]);
            *(short8*)(wp + (size_t)idx * 8) = v;
        }
        return;
    }

    const int bid = blockIdx.x;                         // b*24 + cc*4 + rg
    const int rg  = bid & 3;
    const int cc  = (bid >> 2) % 6;
    const int b   = bid / 24;
    const int h0  = rg * 14;                            // first input row of this group

    // ---- phase 1: global (coalesced) -> LDS, NCHW fp32 -> pair-interleaved bf16 ----
    const float* base = x + ((size_t)(b * CIN + cc * 32) * HWSZ + (size_t)h0 * HWDIM);
    for (int i = tid; i < 16 * 196; i += 256) {         // 16 channel pairs x 196 float4s
        int a = i / 196;                                // channel pair
        int j = i - a * 196;                            // float4 index within 784 pixels
        const float4 f0 = *(const float4*)(base + (size_t)(2 * a)     * HWSZ + j * 4);
        const float4 f1 = *(const float4*)(base + (size_t)(2 * a + 1) * HWSZ + j * 4);
        uint4 u;
        u.x = pk2(f0.x, f1.x);
        u.y = pk2(f0.y, f1.y);
        u.z = pk2(f0.z, f1.z);
        u.w = pk2(f0.w, f1.w);
        *(uint4*)&sp[a * XP_P + j * 4] = u;             // ds_write_b128, conflict-free
    }
    __syncthreads();

    // ---- phase 2: LDS -> global, [pair][pixel] -> [h'][x'][c] with zero x-borders ----
    // chunk slot within pixel is swizzled: s = g ^ ((P>>1)&3), P = padded pixel index
    short* orow = xp + (((size_t)(b * 6 + cc) * PH + (h0 + 1)) * PH) * CK;
    for (int i = tid; i < 14 * 58 * 4; i += 256) {      // 3248 short8 stores
        int g  = i & 3;                                 // logical channel group of 8
        int t  = i >> 2;
        int xq = t % 58;
        int r  = t / 58;                                // local row 0..13
        uint4 u = (uint4){0u, 0u, 0u, 0u};
        if (xq > 0 && xq < 57) {
            int wdx = r * 56 + xq - 1;
            u.x = sp[(4 * g + 0) * XP_P + wdx];
            u.y = sp[(4 * g + 1) * XP_P + wdx];
            u.z = sp[(4 * g + 2) * XP_P + wdx];
            u.w = sp[(4 * g + 3) * XP_P + wdx];
        }
        int P = (h0 + 1 + r) * PH + xq;                 // padded-global pixel index
        int s = g ^ ((P >> 1) & 3);                     // swizzled chunk slot
        *(uint4*)(orow + ((size_t)r * PH + xq) * CK + s * 8) = u;
    }

    // ---- zero pad rows h'=0 (rg==0) and h'=57 (rg==3) ---- (all-zero: swizzle irrelevant)
    if (rg == 0 || rg == 3) {
        int hq = (rg == 0) ? 0 : 57;
        short* prow = xp + (((size_t)(b * 6 + cc) * PH + hq) * PH) * CK;
        for (int i = tid; i < 58 * 4; i += 256)
            *(uint4*)(prow + (size_t)i * 8) = (uint4){0u, 0u, 0u, 0u};
    }
}

// ---------------- main: implicit-GEMM conv, dbuf halo in TWO DISTINCT LDS arrays ----------------
// Round-5 post-mortem fixes, schedule idea retained:
//  * sh0/sh1 are SEPARATE __shared__ arrays -> LLVM NoAlias between ds_read(curbuf) and
//    in-flight global_load_lds(otherbuf); r5's single array + runtime offset forced a
//    conservative vmcnt(0) before the compute reads (stage fully exposed, MfmaUtil 21%).
//  * NO afr-next register prefetch -> compiler sinks afr loads into the off-loop as in r3
//    (VGPR 112, no spill; r5's prefetch held 72 VGPRs across the barrier: VGPR 128 + 36MB
//    scratch stores).
//  * ONE barrier per chunk (6 total vs r3's 11); each STAGE is issued a full compute phase
//    (~2400 cyc) before the barrier that drains it, and always into a buffer whose readers
//    passed the previous barrier (WAR-safe).
// Geometry identical to r3: 256 thr, TH=4, launch_bounds(256,2); LDS 2x22,272 B -> 3 blk/CU.
// Grid 1344 = 8 xcd x 56 slots: og-partner blocks adjacent on the SAME XCD (L2-hit xp).
__global__ __launch_bounds__(256, 2)
void conv_main(const short* __restrict__ xp, const short* __restrict__ wp,
               const float* __restrict__ bias, float* __restrict__ out) {
    __shared__ __align__(16) short sh0[HPC];            // 22,272 B
    __shared__ __align__(16) short sh1[HPC];            // 22,272 B

    const int tid  = threadIdx.x;
    const int u    = blockIdx.x;                        // 0..1343
    const int xcd  = u & 7;
    const int slot = u >> 3;                            // 0..167
    const int og   = slot % 3;
    const int tile = xcd * 56 + slot / 3;               // 0..447
    const int bx   = tile % 14;
    const int bb   = tile / 14;
    const int gh0  = bx * TH;
    const int lane = tid & 63;
    const int wave = tid >> 6;
    const int wm   = wave >> 1;
    const int wn   = wave & 1;
    const int g    = lane >> 4;
    const int col  = lane & 15;

    int pnt[7];
#pragma unroll
    for (int nt = 0; nt < 7; ++nt) {
        int l = wn * 112 + nt * 16 + col;
        pnt[nt] = (l / 56) * PH + (l % 56);             // tile-local pixel index
    }

    floatx4 acc[2][7];
#pragma unroll
    for (int mt = 0; mt < 2; ++mt)
#pragma unroll
        for (int nt = 0; nt < 7; ++nt)
            acc[mt][nt] = (floatx4){0.f, 0.f, 0.f, 0.f};

    const short8* wpk = (const short8*)wp;
    const int wlbase = wave * 64;                       // wave-uniform lds chunk base
    const short* srcb = xp + ((size_t)bb * 6 * (PH * PH) + (size_t)gh0 * PH) * CK;

    // stage chunk CC into distinct LDS array DST (lane-linear, 16B global_load_lds)
#define STAGE(DST, CC)                                                                  \
    do {                                                                                \
        const short* _src = srcb + (size_t)(CC) * (PH * PH) * CK;                       \
        _Pragma("unroll")                                                               \
        for (int _j = 0; _j < 6; ++_j) {                                                \
            int _idx = _j * 256 + tid;                                                  \
            if (_idx < HY * PH * 4) {                    /* 1392 16B chunks */          \
                __builtin_amdgcn_global_load_lds(                                       \
                    (const __attribute__((address_space(1))) void*)(_src + (size_t)_idx * 8), \
                    (__attribute__((address_space(3))) void*)(&DST[(_j * 256 + wlbase) * 8]), \
                    16, 0, 0);                                                          \
            }                                                                           \
        }                                                                               \
    } while (0)

    // compute chunk CC from LDS array BUF; afr loads sink into the off-loop (L2-hit)
#define COMPUTE(BUF, CC)                                                                \
    do {                                                                                \
        short8 afr[9][2];                                                               \
        _Pragma("unroll")                                                               \
        for (int off = 0; off < 9; ++off)                                               \
            _Pragma("unroll")                                                           \
            for (int mt = 0; mt < 2; ++mt)                                              \
                afr[off][mt] = wpk[((og * 6 + (CC)) * 9 + off) * 256 + (wm * 32 + mt * 16 + col) * 4 + g]; \
        _Pragma("unroll")                                                               \
        for (int off = 0; off < 9; ++off) {                                             \
            const int doff = (off / 3) * PH + (off % 3);                                \
            _Pragma("unroll")                                                           \
            for (int nt = 0; nt < 7; ++nt) {                                            \
                int p = pnt[nt] + doff;                                                 \
                int s = ((p >> 1) & 3) ^ g;                                             \
                short8 bfr = *(const short8*)&BUF[(p << 5) + (s << 3)];                 \
                acc[0][nt] = __builtin_amdgcn_mfma_f32_16x16x32_bf16(afr[off][0], bfr, acc[0][nt], 0, 0, 0); \
                acc[1][nt] = __builtin_amdgcn_mfma_f32_16x16x32_bf16(afr[off][1], bfr, acc[1][nt], 0, 0, 0); \
            }                                                                           \
        }                                                                               \
    } while (0)

    // prologue: stage chunks 0,1
    STAGE(sh0, 0);
    STAGE(sh1, 1);
    __syncthreads();                    // vmcnt(0): both stages resident

    // steady state: one barrier per chunk; STAGE(next+1) issued right after the barrier
    // that retires this buffer's readers, drained by the barrier after the NEXT compute.
#pragma unroll 1
    for (int kk = 0; kk < 2; ++kk) {
        COMPUTE(sh0, 2 * kk);
        __syncthreads();                // sh0 readers done; drains STAGE(sh1, 2kk+1... ) already resident
        STAGE(sh0, 2 * kk + 2);
        COMPUTE(sh1, 2 * kk + 1);
        __syncthreads();                // sh1 readers done; drains STAGE(sh0, 2kk+2) (hidden under compute)
        STAGE(sh1, 2 * kk + 3);
    }
    // tail: chunks 4,5 already staged (kk=1 staged sh0<-4? no: kk=1 staged sh0<-4 and sh1<-5)
    COMPUTE(sh0, 4);
    __syncthreads();                    // drains STAGE(sh1, 5) (hidden under compute of chunk 4)
    COMPUTE(sh1, 5);

#undef STAGE
#undef COMPUTE

    // epilogue: D row = g*4 + r, col = lane&15
#pragma unroll
    for (int mt = 0; mt < 2; ++mt) {
        int o = og * 64 + wm * 32 + mt * 16 + g * 4;
#pragma unroll
        for (int nt = 0; nt < 7; ++nt) {
            int l  = wn * 112 + nt * 16 + col;
            int h  = gh0 + l / 56;
            int ww = l % 56;
            size_t base = ((size_t)(bb * COUTN + o) * HWDIM + h) * HWDIM + ww;
            floatx4 v = acc[mt][nt];
#pragma unroll
            for (int r2 = 0; r2 < 4; ++r2)
                out[base + (size_t)r2 * HWSZ] = v[r2] + bias[o + r2];
        }
    }
}

// ---------------- fallback (round-1 kernel) if ws too small ----------------
__global__ __launch_bounds__(256, 2)
void conv3x3_fb(const float* __restrict__ x, const float* __restrict__ w,
                const float* __restrict__ bias, float* __restrict__ out) {
    __shared__ __align__(16) short sh_halo[HY * PH * CK];
    __shared__ __align__(16) short sh_w[9 * MT * CK];
    const int tid = threadIdx.x;
    const int gh0 = blockIdx.x * TH;
    const int o0  = blockIdx.y * MT;
    const int bb  = blockIdx.z;
    const int lane = tid & 63, wave = tid >> 6;
    const int wm = wave >> 1, wn = wave & 1;
    const int g = lane >> 4, col = lane & 15;
    int ly[7], lx[7];
#pragma unroll
    for (int nt = 0; nt < 7; ++nt) {
        int l = wn * 112 + nt * 16 + col;
        ly[nt] = l / 56; lx[nt] = l % 56;
    }
    floatx4 acc[2][7];
#pragma unroll
    for (int mt = 0; mt < 2; ++mt)
#pragma unroll
        for (int nt = 0; nt < 7; ++nt) acc[mt][nt] = (floatx4){0.f,0.f,0.f,0.f};
    for (int cc = 0; cc < NCHUNK; ++cc) {
        const int c0 = cc * CK;
        if (cc) __syncthreads();
        for (int i = tid; i < 4 * HY * PH; i += 256) {
            int xx = i % PH, r = i / PH, y = r % HY, cg = r / HY;
            int gh = gh0 + y - 1, gw = xx - 1;
            bool ok = ((unsigned)gh < 56u) & ((unsigned)gw < 56u);
            const float* src = x + ((size_t)(bb * CIN + c0 + cg * 8) * HWDIM + gh) * HWDIM + gw;
            short8 v;
#pragma unroll
            for (int k = 0; k < 8; ++k) v[k] = f2bf(ok ? src[k * HWSZ] : 0.f);
            *(short8*)&sh_halo[(y * PH + xx) * CK + ((cg ^ ((xx >> 1) & 3)) << 3)] = v;
        }
        for (int i = tid; i < 9 * MT * 4; i += 256) {
            int cg = i & 3, off = (i >> 2) % 9, m = i / 36;
            const float* src = w + (size_t)(o0 + m) * KWT + (c0 + cg * 8) * 9 + off;
            short8 v;
#pragma unroll
            for (int k = 0; k < 8; ++k) v[k] = f2bf(src[k * 9]);
            *(short8*)&sh_w[(off * MT + m) * CK + ((cg ^ ((m >> 1) & 3)) << 3)] = v;
        }
        __syncthreads();
#pragma unroll
        for (int off = 0; off < 9; ++off) {
            const int di = off / 3, dj = off % 3;
            short8 a[2];
#pragma unroll
            for (int mt = 0; mt < 2; ++mt) {
                int m = wm * 32 + mt * 16 + col;
                a[mt] = *(const short8*)&sh_w[(off * MT + m) * CK + ((g ^ ((m >> 1) & 3)) << 3)];
            }
#pragma unroll
            for (int nt = 0; nt < 7; ++nt) {
                int yy = ly[nt] + di, xpp = lx[nt] + dj;
                short8 bfr = *(const short8*)&sh_halo[(yy * PH + xpp) * CK + ((g ^ ((xpp >> 1) & 3)) << 3)];
                acc[0][nt] = __builtin_amdgcn_mfma_f32_16x16x32_bf16(a[0], bfr, acc[0][nt], 0, 0, 0);
                acc[1][nt] = __builtin_amdgcn_mfma_f32_16x16x32_bf16(a[1], bfr, acc[1][nt], 0, 0, 0);
            }
        }
    }
#pragma unroll
    for (int mt = 0; mt < 2; ++mt) {
        int o = o0 + wm * 32 + mt * 16 + g * 4;
#pragma unroll
        for (int nt = 0; nt < 7; ++nt) {
            int l = wn * 112 + nt * 16 + col;
            int h = gh0 + l / 56, ww = l % 56;
            size_t base = ((size_t)(bb * COUTN + o) * HWDIM + h) * HWDIM + ww;
            floatx4 v = acc[mt][nt];
#pragma unroll
            for (int r2 = 0; r2 < 4; ++r2)
                out[base + (size_t)r2 * HWSZ] = v[r2] + bias[o + r2];
        }
    }
}

extern "C" void kernel_launch(void* const* d_in, const int* in_sizes, int n_in,
                              void* d_out, int out_size, void* d_ws, size_t ws_size,
                              hipStream_t stream) {
    const float* x  = (const float*)d_in[0];
    const float* wt = (const float*)d_in[1];
    const float* bi = (const float*)d_in[2];
    float* out = (float*)d_out;

    if (ws_size >= WS_NEEDED) {
        short* xpk = (short*)d_ws;
        short* wpk = xpk + XPACK_SHORTS;
        pack_xw<<<PXBLOCKS + (PWTOT + 255) / 256, 256, 0, stream>>>(x, wt, xpk, wpk);
        conv_main<<<dim3(1344), dim3(256), 0, stream>>>(xpk, wpk, bi, out);
    } else {
        conv3x3_fb<<<dim3(14, 3, 32), dim3(256), 0, stream>>>(x, wt, bi, out);
    }
}